// Round 1
// baseline (904.280 us; speedup 1.0000x reference)
//
#include <hip/hip_runtime.h>
#include <hip/hip_bf16.h>

#define NUM_EXPERTS 8
#define TOPK 2
#define DIM 1024
#define HIDDEN 4096
#define T_TOKENS 2048
#define TOTAL_ROWS (T_TOKENS * TOPK)
#define LDSP 40  // padded LDS row stride (elements) for BK=32 bf16 tiles

typedef __bf16 bf16x8 __attribute__((ext_vector_type(8)));
typedef float f32x4 __attribute__((ext_vector_type(4)));

__device__ __forceinline__ unsigned short f2bf(float f) {
  unsigned int u = __float_as_uint(f);
  u += 0x7FFF + ((u >> 16) & 1);  // round-to-nearest-even
  return (unsigned short)(u >> 16);
}

// ---------------- gating: fp32 scores, top-2, softmax ----------------
__global__ __launch_bounds__(256) void gate_kernel(
    const float* __restrict__ x, const float* __restrict__ gw,
    int* __restrict__ tok_idx, float* __restrict__ tok_w) {
  int wid = threadIdx.x >> 6;
  int lane = threadIdx.x & 63;
  int t = blockIdx.x * 4 + wid;
  if (t >= T_TOKENS) return;

  float xv[16];
#pragma unroll
  for (int i = 0; i < 16; i++) xv[i] = x[t * DIM + lane + i * 64];

  float s[NUM_EXPERTS];
#pragma unroll
  for (int e = 0; e < NUM_EXPERTS; e++) {
    float acc = 0.f;
#pragma unroll
    for (int i = 0; i < 16; i++) acc += xv[i] * gw[e * DIM + lane + i * 64];
#pragma unroll
    for (int off = 32; off; off >>= 1) acc += __shfl_xor(acc, off, 64);
    s[e] = acc;
  }
  if (lane == 0) {
    int i0 = 0;
    float v0 = s[0];
#pragma unroll
    for (int e = 1; e < NUM_EXPERTS; e++)
      if (s[e] > v0) { v0 = s[e]; i0 = e; }   // strict > : lowest index on tie (jax)
    int i1 = -1;
    float v1 = -1e30f;
#pragma unroll
    for (int e = 0; e < NUM_EXPERTS; e++)
      if (e != i0 && s[e] > v1) { v1 = s[e]; i1 = e; }
    float e1 = __expf(v1 - v0);
    float d = 1.f + e1;
    tok_idx[t * 2] = i0;
    tok_idx[t * 2 + 1] = i1;
    tok_w[t * 2] = 1.f / d;
    tok_w[t * 2 + 1] = e1 / d;
  }
}

// ---------------- scatter: build per-expert compact row lists ----------------
__global__ void scatter_kernel(const int* __restrict__ tok_idx,
                               const float* __restrict__ tok_w,
                               int* __restrict__ row_token,
                               float* __restrict__ row_weight,
                               int* __restrict__ counts,
                               int* __restrict__ offsets) {
  __shared__ int sc[NUM_EXPERTS];
  int tid = threadIdx.x;
  if (tid < NUM_EXPERTS) sc[tid] = 0;
  __syncthreads();
  for (int i = tid; i < TOTAL_ROWS; i += blockDim.x)
    atomicAdd(&sc[tok_idx[i]], 1);
  __syncthreads();
  if (tid == 0) {
    int run = 0;
    for (int e = 0; e < NUM_EXPERTS; e++) {
      int c = sc[e];
      counts[e] = c;
      offsets[e] = run;
      sc[e] = run;  // becomes cursor
      run += c;
    }
  }
  __syncthreads();
  for (int i = tid; i < TOTAL_ROWS; i += blockDim.x) {
    int e = tok_idx[i];
    int pos = atomicAdd(&sc[e], 1);
    row_token[pos] = i >> 1;
    row_weight[pos] = tok_w[i];
  }
}

// ---------------- GEMM1: h = silu(X W1^T) * (X W3^T), fused, bf16 out -----
__global__ __launch_bounds__(256) void ffn1_kernel(
    const float* __restrict__ x, const float* __restrict__ w1,
    const float* __restrict__ w3, const int* __restrict__ row_token,
    const int* __restrict__ counts, const int* __restrict__ offsets,
    unsigned short* __restrict__ hbuf) {
  int e = blockIdx.z;
  int cnt = counts[e];
  int m0 = blockIdx.y * 128;
  if (m0 >= cnt) return;
  int n0 = blockIdx.x * 128;
  int row_base = offsets[e];

  __shared__ __align__(16) unsigned short lA[128 * LDSP];
  __shared__ __align__(16) unsigned short lB1[128 * LDSP];
  __shared__ __align__(16) unsigned short lB3[128 * LDSP];

  int tid = threadIdx.x;
  int lane = tid & 63, wid = tid >> 6;
  int quad = lane >> 4, l16 = lane & 15;
  int wm = wid >> 1, wn = wid & 1;

  // per-thread staging descriptors for A (gathered token rows)
  long aoff[4];
  bool aval[4];
#pragma unroll
  for (int it = 0; it < 4; it++) {
    int linear = it * 256 + tid;
    int r = linear >> 3, c4 = linear & 7;
    bool v = (m0 + r) < cnt;
    aval[it] = v;
    int t = v ? row_token[row_base + m0 + r] : 0;
    aoff[it] = (long)t * DIM + c4 * 4;
  }
  const float* w1p = w1 + (long)e * HIDDEN * DIM;
  const float* w3p = w3 + (long)e * HIDDEN * DIM;

  f32x4 acc1[4][4], acc3[4][4];
#pragma unroll
  for (int mi = 0; mi < 4; mi++)
#pragma unroll
    for (int ni = 0; ni < 4; ni++) {
      acc1[mi][ni] = (f32x4){0.f, 0.f, 0.f, 0.f};
      acc3[mi][ni] = (f32x4){0.f, 0.f, 0.f, 0.f};
    }

  for (int k0 = 0; k0 < DIM; k0 += 32) {
#pragma unroll
    for (int it = 0; it < 4; it++) {
      int linear = it * 256 + tid;
      int r = linear >> 3, c4 = linear & 7;
      float4 v = make_float4(0.f, 0.f, 0.f, 0.f);
      if (aval[it]) v = *(const float4*)(x + aoff[it] + k0);
      ushort4 b;
      b.x = f2bf(v.x); b.y = f2bf(v.y); b.z = f2bf(v.z); b.w = f2bf(v.w);
      *(ushort4*)&lA[r * LDSP + c4 * 4] = b;
    }
#pragma unroll
    for (int it = 0; it < 4; it++) {
      int linear = it * 256 + tid;
      int r = linear >> 3, c4 = linear & 7;
      long boff = (long)(n0 + r) * DIM + k0 + c4 * 4;
      float4 v1 = *(const float4*)(w1p + boff);
      float4 v3 = *(const float4*)(w3p + boff);
      ushort4 b1, b3;
      b1.x = f2bf(v1.x); b1.y = f2bf(v1.y); b1.z = f2bf(v1.z); b1.w = f2bf(v1.w);
      b3.x = f2bf(v3.x); b3.y = f2bf(v3.y); b3.z = f2bf(v3.z); b3.w = f2bf(v3.w);
      *(ushort4*)&lB1[r * LDSP + c4 * 4] = b1;
      *(ushort4*)&lB3[r * LDSP + c4 * 4] = b3;
    }
    __syncthreads();

    bf16x8 af[4], b1f[4], b3f[4];
#pragma unroll
    for (int i = 0; i < 4; i++) {
      af[i] = *(const bf16x8*)(const void*)&lA[(wm * 64 + i * 16 + l16) * LDSP + quad * 8];
      b1f[i] = *(const bf16x8*)(const void*)&lB1[(wn * 64 + i * 16 + l16) * LDSP + quad * 8];
      b3f[i] = *(const bf16x8*)(const void*)&lB3[(wn * 64 + i * 16 + l16) * LDSP + quad * 8];
    }
#pragma unroll
    for (int mi = 0; mi < 4; mi++)
#pragma unroll
      for (int ni = 0; ni < 4; ni++) {
        acc1[mi][ni] = __builtin_amdgcn_mfma_f32_16x16x32_bf16(af[mi], b1f[ni], acc1[mi][ni], 0, 0, 0);
        acc3[mi][ni] = __builtin_amdgcn_mfma_f32_16x16x32_bf16(af[mi], b3f[ni], acc3[mi][ni], 0, 0, 0);
      }
    __syncthreads();
  }

  // epilogue: silu(acc1)*acc3 -> bf16 hbuf
#pragma unroll
  for (int mi = 0; mi < 4; mi++) {
#pragma unroll
    for (int r = 0; r < 4; r++) {
      int m = wm * 64 + mi * 16 + quad * 4 + r;
      if (m0 + m < cnt) {
        long rowoff = (long)(row_base + m0 + m) * HIDDEN;
#pragma unroll
        for (int ni = 0; ni < 4; ni++) {
          int n = n0 + wn * 64 + ni * 16 + l16;
          float v1 = acc1[mi][ni][r];
          float v3 = acc3[mi][ni][r];
          float sig = 1.f / (1.f + __expf(-v1));
          hbuf[rowoff + n] = f2bf(v1 * sig * v3);
        }
      }
    }
  }
}

// ---------------- GEMM2: y[t] += w * (h W2^T) ----------------
__global__ __launch_bounds__(256) void ffn2_kernel(
    const unsigned short* __restrict__ hbuf, const float* __restrict__ w2,
    const int* __restrict__ row_token, const float* __restrict__ row_weight,
    const int* __restrict__ counts, const int* __restrict__ offsets,
    float* __restrict__ y) {
  int e = blockIdx.z;
  int cnt = counts[e];
  int m0 = blockIdx.y * 128;
  if (m0 >= cnt) return;
  int n0 = blockIdx.x * 128;
  int row_base = offsets[e];

  __shared__ __align__(16) unsigned short lA[128 * LDSP];
  __shared__ __align__(16) unsigned short lB[128 * LDSP];

  int tid = threadIdx.x;
  int lane = tid & 63, wid = tid >> 6;
  int quad = lane >> 4, l16 = lane & 15;
  int wm = wid >> 1, wn = wid & 1;

  const float* w2p = w2 + (long)e * DIM * HIDDEN;

  f32x4 acc[4][4];
#pragma unroll
  for (int mi = 0; mi < 4; mi++)
#pragma unroll
    for (int ni = 0; ni < 4; ni++) acc[mi][ni] = (f32x4){0.f, 0.f, 0.f, 0.f};

  for (int k0 = 0; k0 < HIDDEN; k0 += 32) {
    // stage A (already bf16): 128x32 elems = 512 16B-chunks, 2 per thread
#pragma unroll
    for (int it = 0; it < 2; it++) {
      int linear = it * 256 + tid;
      int r = linear >> 2, c8 = linear & 3;
      float4 v = make_float4(0.f, 0.f, 0.f, 0.f);
      if (m0 + r < cnt)
        v = *(const float4*)(hbuf + (long)(row_base + m0 + r) * HIDDEN + k0 + c8 * 8);
      *(float4*)&lA[r * LDSP + c8 * 8] = v;
    }
    // stage B (w2 fp32 -> bf16)
#pragma unroll
    for (int it = 0; it < 4; it++) {
      int linear = it * 256 + tid;
      int r = linear >> 3, c4 = linear & 7;
      float4 v = *(const float4*)(w2p + (long)(n0 + r) * HIDDEN + k0 + c4 * 4);
      ushort4 b;
      b.x = f2bf(v.x); b.y = f2bf(v.y); b.z = f2bf(v.z); b.w = f2bf(v.w);
      *(ushort4*)&lB[r * LDSP + c4 * 4] = b;
    }
    __syncthreads();

    bf16x8 af[4], bf[4];
#pragma unroll
    for (int i = 0; i < 4; i++) {
      af[i] = *(const bf16x8*)(const void*)&lA[(wm * 64 + i * 16 + l16) * LDSP + quad * 8];
      bf[i] = *(const bf16x8*)(const void*)&lB[(wn * 64 + i * 16 + l16) * LDSP + quad * 8];
    }
#pragma unroll
    for (int mi = 0; mi < 4; mi++)
#pragma unroll
      for (int ni = 0; ni < 4; ni++)
        acc[mi][ni] = __builtin_amdgcn_mfma_f32_16x16x32_bf16(af[mi], bf[ni], acc[mi][ni], 0, 0, 0);
    __syncthreads();
  }

#pragma unroll
  for (int mi = 0; mi < 4; mi++) {
#pragma unroll
    for (int r = 0; r < 4; r++) {
      int m = wm * 64 + mi * 16 + quad * 4 + r;
      if (m0 + m < cnt) {
        int t = row_token[row_base + m0 + m];
        float wgt = row_weight[row_base + m0 + m];
        long yoff = (long)t * DIM + n0 + wn * 64;
#pragma unroll
        for (int ni = 0; ni < 4; ni++)
          atomicAdd(&y[yoff + ni * 16 + l16], wgt * acc[mi][ni][r]);
      }
    }
  }
}

extern "C" void kernel_launch(void* const* d_in, const int* in_sizes, int n_in,
                              void* d_out, int out_size, void* d_ws, size_t ws_size,
                              hipStream_t stream) {
  const float* x = (const float*)d_in[0];
  const float* gw = (const float*)d_in[1];
  const float* w1 = (const float*)d_in[2];
  const float* w2 = (const float*)d_in[3];
  const float* w3 = (const float*)d_in[4];
  float* y = (float*)d_out;

  char* ws = (char*)d_ws;
  int* row_token = (int*)ws;                        // 4096 ints   = 16384 B
  float* row_weight = (float*)(ws + 16384);         // 4096 floats = 16384 B
  int* counts = (int*)(ws + 32768);                 // 8 ints
  int* offsets = (int*)(ws + 32768 + 32);           // 8 ints
  int* tok_idx = (int*)(ws + 32896);                // 4096 ints
  float* tok_w = (float*)(ws + 32896 + 16384);      // 4096 floats
  unsigned short* hbuf = (unsigned short*)(ws + 65664);  // 4096*4096 bf16 = 33.5 MB

  hipMemsetAsync(d_out, 0, (size_t)T_TOKENS * DIM * sizeof(float), stream);
  gate_kernel<<<T_TOKENS / 4, 256, 0, stream>>>(x, gw, tok_idx, tok_w);
  scatter_kernel<<<1, 256, 0, stream>>>(tok_idx, tok_w, row_token, row_weight, counts, offsets);
  ffn1_kernel<<<dim3(HIDDEN / 128, T_TOKENS / 128, NUM_EXPERTS), 256, 0, stream>>>(
      x, w1, w3, row_token, counts, offsets, hbuf);
  ffn2_kernel<<<dim3(DIM / 128, T_TOKENS / 128, NUM_EXPERTS), 256, 0, stream>>>(
      hbuf, w2, row_token, row_weight, counts, offsets, y);
}

// Round 2
// 759.631 us; speedup vs baseline: 1.1904x; 1.1904x over previous
//
#include <hip/hip_runtime.h>
#include <hip/hip_bf16.h>

#define NUM_EXPERTS 8
#define TOPK 2
#define DIM 1024
#define HIDDEN 4096
#define T_TOKENS 2048
#define TOTAL_ROWS (T_TOKENS * TOPK)
#define LDSP 40  // padded stride for the slow-path kernels only

typedef __bf16 bf16x8 __attribute__((ext_vector_type(8)));
typedef float f32x4 __attribute__((ext_vector_type(4)));

__device__ __forceinline__ unsigned short f2bf(float f) {
  unsigned int u = __float_as_uint(f);
  u += 0x7FFF + ((u >> 16) & 1);  // round-to-nearest-even
  return (unsigned short)(u >> 16);
}

__device__ __forceinline__ void gl_lds16(const void* g, void* l) {
  __builtin_amdgcn_global_load_lds(
      (const __attribute__((address_space(1))) unsigned int*)g,
      (__attribute__((address_space(3))) unsigned int*)l, 16, 0, 0);
}

// ---------------- fp32 -> bf16 cast (streaming) ----------------
__global__ __launch_bounds__(256) void cast_kernel(
    const float* __restrict__ src, unsigned short* __restrict__ dst, int n8) {
  int i = blockIdx.x * blockDim.x + threadIdx.x;
  int stride = gridDim.x * blockDim.x;
  for (; i < n8; i += stride) {
    float4 a = ((const float4*)src)[i * 2];
    float4 b = ((const float4*)src)[i * 2 + 1];
    ushort4 o0, o1;
    o0.x = f2bf(a.x); o0.y = f2bf(a.y); o0.z = f2bf(a.z); o0.w = f2bf(a.w);
    o1.x = f2bf(b.x); o1.y = f2bf(b.y); o1.z = f2bf(b.z); o1.w = f2bf(b.w);
    ((ushort4*)dst)[i * 2] = o0;
    ((ushort4*)dst)[i * 2 + 1] = o1;
  }
}

// ---------------- gating: fp32 scores, top-2, softmax ----------------
__global__ __launch_bounds__(256) void gate_kernel(
    const float* __restrict__ x, const float* __restrict__ gw,
    int* __restrict__ tok_idx, float* __restrict__ tok_w) {
  int wid = threadIdx.x >> 6;
  int lane = threadIdx.x & 63;
  int t = blockIdx.x * 4 + wid;
  if (t >= T_TOKENS) return;

  float xv[16];
#pragma unroll
  for (int i = 0; i < 16; i++) xv[i] = x[t * DIM + lane + i * 64];

  float s[NUM_EXPERTS];
#pragma unroll
  for (int e = 0; e < NUM_EXPERTS; e++) {
    float acc = 0.f;
#pragma unroll
    for (int i = 0; i < 16; i++) acc += xv[i] * gw[e * DIM + lane + i * 64];
#pragma unroll
    for (int off = 32; off; off >>= 1) acc += __shfl_xor(acc, off, 64);
    s[e] = acc;
  }
  if (lane == 0) {
    int i0 = 0;
    float v0 = s[0];
#pragma unroll
    for (int e = 1; e < NUM_EXPERTS; e++)
      if (s[e] > v0) { v0 = s[e]; i0 = e; }
    int i1 = -1;
    float v1 = -1e30f;
#pragma unroll
    for (int e = 0; e < NUM_EXPERTS; e++)
      if (e != i0 && s[e] > v1) { v1 = s[e]; i1 = e; }
    float e1 = __expf(v1 - v0);
    float d = 1.f + e1;
    tok_idx[t * 2] = i0;
    tok_idx[t * 2 + 1] = i1;
    tok_w[t * 2] = 1.f / d;
    tok_w[t * 2 + 1] = e1 / d;
  }
}

// ---------------- scatter: per-expert compact row lists ----------------
__global__ void scatter_kernel(const int* __restrict__ tok_idx,
                               const float* __restrict__ tok_w,
                               int* __restrict__ row_token,
                               float* __restrict__ row_weight,
                               int* __restrict__ counts,
                               int* __restrict__ offsets) {
  __shared__ int sc[NUM_EXPERTS];
  int tid = threadIdx.x;
  if (tid < NUM_EXPERTS) sc[tid] = 0;
  __syncthreads();
  for (int i = tid; i < TOTAL_ROWS; i += blockDim.x)
    atomicAdd(&sc[tok_idx[i]], 1);
  __syncthreads();
  if (tid == 0) {
    int run = 0;
    for (int e = 0; e < NUM_EXPERTS; e++) {
      int c = sc[e];
      counts[e] = c;
      offsets[e] = run;
      sc[e] = run;
      run += c;
    }
  }
  __syncthreads();
  for (int i = tid; i < TOTAL_ROWS; i += blockDim.x) {
    int e = tok_idx[i];
    int pos = atomicAdd(&sc[e], 1);
    row_token[pos] = i >> 1;
    row_weight[pos] = tok_w[i];
  }
}

// ======================= FAST PATH (bf16 weights in ws) =======================

// GEMM1: h = silu(X W1^T) * (X W3^T), 128x128 tile, global_load_lds staging
__global__ __launch_bounds__(256) void ffn1_fast(
    const unsigned short* __restrict__ xb, const unsigned short* __restrict__ w1b,
    const unsigned short* __restrict__ w3b, const int* __restrict__ row_token,
    const int* __restrict__ counts, const int* __restrict__ offsets,
    unsigned short* __restrict__ hbuf) {
  int e = blockIdx.z;
  int cnt = counts[e];
  int m0 = blockIdx.y * 128;
  if (m0 >= cnt) return;
  int n0 = blockIdx.x * 128;
  int row_base = offsets[e];

  __shared__ __align__(16) unsigned short lA[128 * 32];
  __shared__ __align__(16) unsigned short lB1[128 * 32];
  __shared__ __align__(16) unsigned short lB3[128 * 32];

  int tid = threadIdx.x;
  int lane = tid & 63, wid = tid >> 6;
  int quad = lane >> 4, l16 = lane & 15;
  int wm = wid >> 1, wn = wid & 1;

  // A staging: 512 16B-chunks (128 rows x 4 segs), 2 per thread; gathered rows
  long aoff[2];
#pragma unroll
  for (int it = 0; it < 2; it++) {
    int c = it * 256 + tid;
    int r = c >> 2, seg = c & 3;
    int t = (m0 + r) < cnt ? row_token[row_base + m0 + r] : 0;
    aoff[it] = (long)t * DIM + seg * 8;
  }
  const unsigned short* w1p = w1b + (long)e * HIDDEN * DIM + (long)n0 * DIM;
  const unsigned short* w3p = w3b + (long)e * HIDDEN * DIM + (long)n0 * DIM;

  f32x4 acc1[4][4], acc3[4][4];
#pragma unroll
  for (int mi = 0; mi < 4; mi++)
#pragma unroll
    for (int ni = 0; ni < 4; ni++) {
      acc1[mi][ni] = (f32x4){0.f, 0.f, 0.f, 0.f};
      acc3[mi][ni] = (f32x4){0.f, 0.f, 0.f, 0.f};
    }

  for (int k0 = 0; k0 < DIM; k0 += 32) {
#pragma unroll
    for (int it = 0; it < 2; it++) {
      int c = it * 256 + tid;
      long boff = (long)(c >> 2) * DIM + (c & 3) * 8 + k0;
      gl_lds16(xb + aoff[it] + k0, &lA[c * 8]);
      gl_lds16(w1p + boff, &lB1[c * 8]);
      gl_lds16(w3p + boff, &lB3[c * 8]);
    }
    __syncthreads();

    bf16x8 af[4], b1f[4], b3f[4];
#pragma unroll
    for (int i = 0; i < 4; i++) {
      af[i]  = *(const bf16x8*)(const void*)&lA[(wm * 64 + i * 16 + l16) * 32 + quad * 8];
      b1f[i] = *(const bf16x8*)(const void*)&lB1[(wn * 64 + i * 16 + l16) * 32 + quad * 8];
      b3f[i] = *(const bf16x8*)(const void*)&lB3[(wn * 64 + i * 16 + l16) * 32 + quad * 8];
    }
#pragma unroll
    for (int mi = 0; mi < 4; mi++)
#pragma unroll
      for (int ni = 0; ni < 4; ni++) {
        acc1[mi][ni] = __builtin_amdgcn_mfma_f32_16x16x32_bf16(af[mi], b1f[ni], acc1[mi][ni], 0, 0, 0);
        acc3[mi][ni] = __builtin_amdgcn_mfma_f32_16x16x32_bf16(af[mi], b3f[ni], acc3[mi][ni], 0, 0, 0);
      }
    __syncthreads();
  }

#pragma unroll
  for (int mi = 0; mi < 4; mi++) {
#pragma unroll
    for (int r = 0; r < 4; r++) {
      int m = wm * 64 + mi * 16 + quad * 4 + r;
      if (m0 + m < cnt) {
        long rowoff = (long)(row_base + m0 + m) * HIDDEN;
#pragma unroll
        for (int ni = 0; ni < 4; ni++) {
          int n = n0 + wn * 64 + ni * 16 + l16;
          float v1 = acc1[mi][ni][r];
          float v3 = acc3[mi][ni][r];
          float sig = 1.f / (1.f + __expf(-v1));
          hbuf[rowoff + n] = f2bf(v1 * sig * v3);
        }
      }
    }
  }
}

// GEMM2: y[t] += w * (h W2^T), 64x128 tile (more blocks), global_load_lds
__global__ __launch_bounds__(256) void ffn2_fast(
    const unsigned short* __restrict__ hbuf, const unsigned short* __restrict__ w2b,
    const int* __restrict__ row_token, const float* __restrict__ row_weight,
    const int* __restrict__ counts, const int* __restrict__ offsets,
    float* __restrict__ y) {
  int e = blockIdx.z;
  int cnt = counts[e];
  int m0 = blockIdx.y * 64;
  if (m0 >= cnt) return;
  int n0 = blockIdx.x * 128;
  int row_base = offsets[e];

  __shared__ __align__(16) unsigned short lA[64 * 32];
  __shared__ __align__(16) unsigned short lB[128 * 32];

  int tid = threadIdx.x;
  int lane = tid & 63, wid = tid >> 6;
  int quad = lane >> 4, l16 = lane & 15;
  int wm = wid >> 1, wn = wid & 1;  // wave tile: 32 (M) x 64 (N)

  // A staging: 64x32 = 256 chunks, 1 per thread
  int ar = tid >> 2, aseg = tid & 3;
  int arow = (m0 + ar) < cnt ? (row_base + m0 + ar) : row_base;
  long aoff = (long)arow * HIDDEN + aseg * 8;

  const unsigned short* w2p = w2b + (long)e * DIM * HIDDEN + (long)n0 * HIDDEN;

  f32x4 acc[2][4];
#pragma unroll
  for (int mi = 0; mi < 2; mi++)
#pragma unroll
    for (int ni = 0; ni < 4; ni++) acc[mi][ni] = (f32x4){0.f, 0.f, 0.f, 0.f};

  for (int k0 = 0; k0 < HIDDEN; k0 += 32) {
    gl_lds16(hbuf + aoff + k0, &lA[tid * 8]);
#pragma unroll
    for (int it = 0; it < 2; it++) {
      int c = it * 256 + tid;
      long boff = (long)(c >> 2) * HIDDEN + (c & 3) * 8 + k0;
      gl_lds16(w2p + boff, &lB[c * 8]);
    }
    __syncthreads();

    bf16x8 af[2], bf[4];
#pragma unroll
    for (int i = 0; i < 2; i++)
      af[i] = *(const bf16x8*)(const void*)&lA[(wm * 32 + i * 16 + l16) * 32 + quad * 8];
#pragma unroll
    for (int i = 0; i < 4; i++)
      bf[i] = *(const bf16x8*)(const void*)&lB[(wn * 64 + i * 16 + l16) * 32 + quad * 8];
#pragma unroll
    for (int mi = 0; mi < 2; mi++)
#pragma unroll
      for (int ni = 0; ni < 4; ni++)
        acc[mi][ni] = __builtin_amdgcn_mfma_f32_16x16x32_bf16(af[mi], bf[ni], acc[mi][ni], 0, 0, 0);
    __syncthreads();
  }

#pragma unroll
  for (int mi = 0; mi < 2; mi++) {
#pragma unroll
    for (int r = 0; r < 4; r++) {
      int m = wm * 32 + mi * 16 + quad * 4 + r;
      if (m0 + m < cnt) {
        int t = row_token[row_base + m0 + m];
        float wgt = row_weight[row_base + m0 + m];
        long yoff = (long)t * DIM + n0 + wn * 64;
#pragma unroll
        for (int ni = 0; ni < 4; ni++)
          atomicAdd(&y[yoff + ni * 16 + l16], wgt * acc[mi][ni][r]);
      }
    }
  }
}

// ======================= SLOW PATH (round-1, convert-on-the-fly) =============

__global__ __launch_bounds__(256) void ffn1_slow(
    const float* __restrict__ x, const float* __restrict__ w1,
    const float* __restrict__ w3, const int* __restrict__ row_token,
    const int* __restrict__ counts, const int* __restrict__ offsets,
    unsigned short* __restrict__ hbuf) {
  int e = blockIdx.z;
  int cnt = counts[e];
  int m0 = blockIdx.y * 128;
  if (m0 >= cnt) return;
  int n0 = blockIdx.x * 128;
  int row_base = offsets[e];

  __shared__ __align__(16) unsigned short lA[128 * LDSP];
  __shared__ __align__(16) unsigned short lB1[128 * LDSP];
  __shared__ __align__(16) unsigned short lB3[128 * LDSP];

  int tid = threadIdx.x;
  int lane = tid & 63, wid = tid >> 6;
  int quad = lane >> 4, l16 = lane & 15;
  int wm = wid >> 1, wn = wid & 1;

  long aoff[4];
  bool aval[4];
#pragma unroll
  for (int it = 0; it < 4; it++) {
    int linear = it * 256 + tid;
    int r = linear >> 3, c4 = linear & 7;
    bool v = (m0 + r) < cnt;
    aval[it] = v;
    int t = v ? row_token[row_base + m0 + r] : 0;
    aoff[it] = (long)t * DIM + c4 * 4;
  }
  const float* w1p = w1 + (long)e * HIDDEN * DIM;
  const float* w3p = w3 + (long)e * HIDDEN * DIM;

  f32x4 acc1[4][4], acc3[4][4];
#pragma unroll
  for (int mi = 0; mi < 4; mi++)
#pragma unroll
    for (int ni = 0; ni < 4; ni++) {
      acc1[mi][ni] = (f32x4){0.f, 0.f, 0.f, 0.f};
      acc3[mi][ni] = (f32x4){0.f, 0.f, 0.f, 0.f};
    }

  for (int k0 = 0; k0 < DIM; k0 += 32) {
#pragma unroll
    for (int it = 0; it < 4; it++) {
      int linear = it * 256 + tid;
      int r = linear >> 3, c4 = linear & 7;
      float4 v = make_float4(0.f, 0.f, 0.f, 0.f);
      if (aval[it]) v = *(const float4*)(x + aoff[it] + k0);
      ushort4 b;
      b.x = f2bf(v.x); b.y = f2bf(v.y); b.z = f2bf(v.z); b.w = f2bf(v.w);
      *(ushort4*)&lA[r * LDSP + c4 * 4] = b;
    }
#pragma unroll
    for (int it = 0; it < 4; it++) {
      int linear = it * 256 + tid;
      int r = linear >> 3, c4 = linear & 7;
      long boff = (long)(n0 + r) * DIM + k0 + c4 * 4;
      float4 v1 = *(const float4*)(w1p + boff);
      float4 v3 = *(const float4*)(w3p + boff);
      ushort4 b1, b3;
      b1.x = f2bf(v1.x); b1.y = f2bf(v1.y); b1.z = f2bf(v1.z); b1.w = f2bf(v1.w);
      b3.x = f2bf(v3.x); b3.y = f2bf(v3.y); b3.z = f2bf(v3.z); b3.w = f2bf(v3.w);
      *(ushort4*)&lB1[r * LDSP + c4 * 4] = b1;
      *(ushort4*)&lB3[r * LDSP + c4 * 4] = b3;
    }
    __syncthreads();

    bf16x8 af[4], b1f[4], b3f[4];
#pragma unroll
    for (int i = 0; i < 4; i++) {
      af[i]  = *(const bf16x8*)(const void*)&lA[(wm * 64 + i * 16 + l16) * LDSP + quad * 8];
      b1f[i] = *(const bf16x8*)(const void*)&lB1[(wn * 64 + i * 16 + l16) * LDSP + quad * 8];
      b3f[i] = *(const bf16x8*)(const void*)&lB3[(wn * 64 + i * 16 + l16) * LDSP + quad * 8];
    }
#pragma unroll
    for (int mi = 0; mi < 4; mi++)
#pragma unroll
      for (int ni = 0; ni < 4; ni++) {
        acc1[mi][ni] = __builtin_amdgcn_mfma_f32_16x16x32_bf16(af[mi], b1f[ni], acc1[mi][ni], 0, 0, 0);
        acc3[mi][ni] = __builtin_amdgcn_mfma_f32_16x16x32_bf16(af[mi], b3f[ni], acc3[mi][ni], 0, 0, 0);
      }
    __syncthreads();
  }

#pragma unroll
  for (int mi = 0; mi < 4; mi++) {
#pragma unroll
    for (int r = 0; r < 4; r++) {
      int m = wm * 64 + mi * 16 + quad * 4 + r;
      if (m0 + m < cnt) {
        long rowoff = (long)(row_base + m0 + m) * HIDDEN;
#pragma unroll
        for (int ni = 0; ni < 4; ni++) {
          int n = n0 + wn * 64 + ni * 16 + l16;
          float v1 = acc1[mi][ni][r];
          float v3 = acc3[mi][ni][r];
          float sig = 1.f / (1.f + __expf(-v1));
          hbuf[rowoff + n] = f2bf(v1 * sig * v3);
        }
      }
    }
  }
}

__global__ __launch_bounds__(256) void ffn2_slow(
    const unsigned short* __restrict__ hbuf, const float* __restrict__ w2,
    const int* __restrict__ row_token, const float* __restrict__ row_weight,
    const int* __restrict__ counts, const int* __restrict__ offsets,
    float* __restrict__ y) {
  int e = blockIdx.z;
  int cnt = counts[e];
  int m0 = blockIdx.y * 128;
  if (m0 >= cnt) return;
  int n0 = blockIdx.x * 128;
  int row_base = offsets[e];

  __shared__ __align__(16) unsigned short lA[128 * LDSP];
  __shared__ __align__(16) unsigned short lB[128 * LDSP];

  int tid = threadIdx.x;
  int lane = tid & 63, wid = tid >> 6;
  int quad = lane >> 4, l16 = lane & 15;
  int wm = wid >> 1, wn = wid & 1;

  const float* w2p = w2 + (long)e * DIM * HIDDEN;

  f32x4 acc[4][4];
#pragma unroll
  for (int mi = 0; mi < 4; mi++)
#pragma unroll
    for (int ni = 0; ni < 4; ni++) acc[mi][ni] = (f32x4){0.f, 0.f, 0.f, 0.f};

  for (int k0 = 0; k0 < HIDDEN; k0 += 32) {
#pragma unroll
    for (int it = 0; it < 2; it++) {
      int linear = it * 256 + tid;
      int r = linear >> 2, c8 = linear & 3;
      float4 v = make_float4(0.f, 0.f, 0.f, 0.f);
      if (m0 + r < cnt)
        v = *(const float4*)(hbuf + (long)(row_base + m0 + r) * HIDDEN + k0 + c8 * 8);
      *(float4*)&lA[r * LDSP + c8 * 8] = v;
    }
#pragma unroll
    for (int it = 0; it < 4; it++) {
      int linear = it * 256 + tid;
      int r = linear >> 3, c4 = linear & 7;
      float4 v = *(const float4*)(w2p + (long)(n0 + r) * HIDDEN + k0 + c4 * 4);
      ushort4 b;
      b.x = f2bf(v.x); b.y = f2bf(v.y); b.z = f2bf(v.z); b.w = f2bf(v.w);
      *(ushort4*)&lB[r * LDSP + c4 * 4] = b;
    }
    __syncthreads();

    bf16x8 af[4], bfr[4];
#pragma unroll
    for (int i = 0; i < 4; i++) {
      af[i]  = *(const bf16x8*)(const void*)&lA[(wm * 64 + i * 16 + l16) * LDSP + quad * 8];
      bfr[i] = *(const bf16x8*)(const void*)&lB[(wn * 64 + i * 16 + l16) * LDSP + quad * 8];
    }
#pragma unroll
    for (int mi = 0; mi < 4; mi++)
#pragma unroll
      for (int ni = 0; ni < 4; ni++)
        acc[mi][ni] = __builtin_amdgcn_mfma_f32_16x16x32_bf16(af[mi], bfr[ni], acc[mi][ni], 0, 0, 0);
    __syncthreads();
  }

#pragma unroll
  for (int mi = 0; mi < 4; mi++) {
#pragma unroll
    for (int r = 0; r < 4; r++) {
      int m = wm * 64 + mi * 16 + quad * 4 + r;
      if (m0 + m < cnt) {
        int t = row_token[row_base + m0 + m];
        float wgt = row_weight[row_base + m0 + m];
        long yoff = (long)t * DIM + n0 + wn * 64;
#pragma unroll
        for (int ni = 0; ni < 4; ni++)
          atomicAdd(&y[yoff + ni * 16 + l16], wgt * acc[mi][ni][r]);
      }
    }
  }
}

extern "C" void kernel_launch(void* const* d_in, const int* in_sizes, int n_in,
                              void* d_out, int out_size, void* d_ws, size_t ws_size,
                              hipStream_t stream) {
  const float* x = (const float*)d_in[0];
  const float* gw = (const float*)d_in[1];
  const float* w1 = (const float*)d_in[2];
  const float* w2 = (const float*)d_in[3];
  const float* w3 = (const float*)d_in[4];
  float* y = (float*)d_out;

  char* ws = (char*)d_ws;
  int* row_token = (int*)ws;
  float* row_weight = (float*)(ws + 16384);
  int* counts = (int*)(ws + 32768);
  int* offsets = (int*)(ws + 32768 + 32);
  int* tok_idx = (int*)(ws + 32896);
  float* tok_w = (float*)(ws + 32896 + 16384);
  // big buffers
  const size_t HBUF_OFF = 65664;                        // 4096*4096 bf16 = 33,554,432
  const size_t XB_OFF   = HBUF_OFF + 33554432ull;       // 2048*1024 bf16 = 4,194,304
  const size_t W1B_OFF  = XB_OFF + 4194304ull;          // 33,554,432 bf16 = 67,108,864
  const size_t W2B_OFF  = W1B_OFF + 67108864ull;
  const size_t W3B_OFF  = W2B_OFF + 67108864ull;
  const size_t NEED     = W3B_OFF + 67108864ull;        // = 239,140,992
  unsigned short* hbuf = (unsigned short*)(ws + HBUF_OFF);

  hipMemsetAsync(d_out, 0, (size_t)T_TOKENS * DIM * sizeof(float), stream);
  gate_kernel<<<T_TOKENS / 4, 256, 0, stream>>>(x, gw, tok_idx, tok_w);
  scatter_kernel<<<1, 256, 0, stream>>>(tok_idx, tok_w, row_token, row_weight, counts, offsets);

  if (ws_size >= NEED) {
    unsigned short* xb  = (unsigned short*)(ws + XB_OFF);
    unsigned short* w1b = (unsigned short*)(ws + W1B_OFF);
    unsigned short* w2b = (unsigned short*)(ws + W2B_OFF);
    unsigned short* w3b = (unsigned short*)(ws + W3B_OFF);
    const int NW8 = NUM_EXPERTS * HIDDEN * DIM / 8;     // 4,194,304
    cast_kernel<<<512, 256, 0, stream>>>(x, xb, T_TOKENS * DIM / 8);
    cast_kernel<<<2048, 256, 0, stream>>>(w1, w1b, NW8);
    cast_kernel<<<2048, 256, 0, stream>>>(w3, w3b, NW8);
    cast_kernel<<<2048, 256, 0, stream>>>(w2, w2b, NW8);
    ffn1_fast<<<dim3(HIDDEN / 128, T_TOKENS / 128, NUM_EXPERTS), 256, 0, stream>>>(
        xb, w1b, w3b, row_token, counts, offsets, hbuf);
    ffn2_fast<<<dim3(DIM / 128, T_TOKENS / 64, NUM_EXPERTS), 256, 0, stream>>>(
        hbuf, w2b, row_token, row_weight, counts, offsets, y);
  } else {
    ffn1_slow<<<dim3(HIDDEN / 128, T_TOKENS / 128, NUM_EXPERTS), 256, 0, stream>>>(
        x, w1, w3, row_token, counts, offsets, hbuf);
    ffn2_slow<<<dim3(DIM / 128, T_TOKENS / 128, NUM_EXPERTS), 256, 0, stream>>>(
        hbuf, w2, row_token, row_weight, counts, offsets, y);
  }
}

// Round 3
// 694.402 us; speedup vs baseline: 1.3022x; 1.0939x over previous
//
#include <hip/hip_runtime.h>
#include <hip/hip_bf16.h>

#define NUM_EXPERTS 8
#define TOPK 2
#define DIM 1024
#define HIDDEN 4096
#define T_TOKENS 2048
#define TOTAL_ROWS (T_TOKENS * TOPK)
#define LDSP 40  // padded stride for the slow-path kernels only

typedef __bf16 bf16x8 __attribute__((ext_vector_type(8)));
typedef float f32x4 __attribute__((ext_vector_type(4)));

__device__ __forceinline__ unsigned short f2bf(float f) {
  unsigned int u = __float_as_uint(f);
  u += 0x7FFF + ((u >> 16) & 1);  // round-to-nearest-even
  return (unsigned short)(u >> 16);
}

__device__ __forceinline__ void gl_lds16(const void* g, void* l) {
  __builtin_amdgcn_global_load_lds(
      (const __attribute__((address_space(1))) unsigned int*)g,
      (__attribute__((address_space(3))) unsigned int*)l, 16, 0, 0);
}

// s_waitcnt with vmcnt=N only (expcnt=7, lgkmcnt=15 -> don't wait)
#define WAIT_VM(N) __builtin_amdgcn_s_waitcnt(0x0F70 | (N))
#define BARRIER() __builtin_amdgcn_s_barrier()

// ---------------- fp32 -> bf16 cast (streaming) ----------------
__global__ __launch_bounds__(256) void cast_kernel(
    const float* __restrict__ src, unsigned short* __restrict__ dst, int n8) {
  int i = blockIdx.x * blockDim.x + threadIdx.x;
  int stride = gridDim.x * blockDim.x;
  for (; i < n8; i += stride) {
    float4 a = ((const float4*)src)[i * 2];
    float4 b = ((const float4*)src)[i * 2 + 1];
    ushort4 o0, o1;
    o0.x = f2bf(a.x); o0.y = f2bf(a.y); o0.z = f2bf(a.z); o0.w = f2bf(a.w);
    o1.x = f2bf(b.x); o1.y = f2bf(b.y); o1.z = f2bf(b.z); o1.w = f2bf(b.w);
    ((ushort4*)dst)[i * 2] = o0;
    ((ushort4*)dst)[i * 2 + 1] = o1;
  }
}

// ---------------- gating: fp32 scores, top-2, softmax ----------------
__global__ __launch_bounds__(256) void gate_kernel(
    const float* __restrict__ x, const float* __restrict__ gw,
    int* __restrict__ tok_idx, float* __restrict__ tok_w) {
  int wid = threadIdx.x >> 6;
  int lane = threadIdx.x & 63;
  int t = blockIdx.x * 4 + wid;
  if (t >= T_TOKENS) return;

  float xv[16];
#pragma unroll
  for (int i = 0; i < 16; i++) xv[i] = x[t * DIM + lane + i * 64];

  float s[NUM_EXPERTS];
#pragma unroll
  for (int e = 0; e < NUM_EXPERTS; e++) {
    float acc = 0.f;
#pragma unroll
    for (int i = 0; i < 16; i++) acc += xv[i] * gw[e * DIM + lane + i * 64];
#pragma unroll
    for (int off = 32; off; off >>= 1) acc += __shfl_xor(acc, off, 64);
    s[e] = acc;
  }
  if (lane == 0) {
    int i0 = 0;
    float v0 = s[0];
#pragma unroll
    for (int e = 1; e < NUM_EXPERTS; e++)
      if (s[e] > v0) { v0 = s[e]; i0 = e; }
    int i1 = -1;
    float v1 = -1e30f;
#pragma unroll
    for (int e = 0; e < NUM_EXPERTS; e++)
      if (e != i0 && s[e] > v1) { v1 = s[e]; i1 = e; }
    float e1 = __expf(v1 - v0);
    float d = 1.f + e1;
    tok_idx[t * 2] = i0;
    tok_idx[t * 2 + 1] = i1;
    tok_w[t * 2] = 1.f / d;
    tok_w[t * 2 + 1] = e1 / d;
  }
}

// ---------------- scatter: per-expert compact row lists ----------------
__global__ void scatter_kernel(const int* __restrict__ tok_idx,
                               const float* __restrict__ tok_w,
                               int* __restrict__ row_token,
                               float* __restrict__ row_weight,
                               int* __restrict__ counts,
                               int* __restrict__ offsets) {
  __shared__ int sc[NUM_EXPERTS];
  int tid = threadIdx.x;
  if (tid < NUM_EXPERTS) sc[tid] = 0;
  __syncthreads();
  for (int i = tid; i < TOTAL_ROWS; i += blockDim.x)
    atomicAdd(&sc[tok_idx[i]], 1);
  __syncthreads();
  if (tid == 0) {
    int run = 0;
    for (int e = 0; e < NUM_EXPERTS; e++) {
      int c = sc[e];
      counts[e] = c;
      offsets[e] = run;
      sc[e] = run;
      run += c;
    }
  }
  __syncthreads();
  for (int i = tid; i < TOTAL_ROWS; i += blockDim.x) {
    int e = tok_idx[i];
    int pos = atomicAdd(&sc[e], 1);
    row_token[pos] = i >> 1;
    row_weight[pos] = tok_w[i];
  }
}

// ======================= FAST PATH (bf16 weights in ws) =======================

// GEMM1: h = silu(X W1^T) * (X W3^T), 128x128 tile, pipelined dbuf staging
__global__ __launch_bounds__(256) void ffn1_fast(
    const unsigned short* __restrict__ xb, const unsigned short* __restrict__ w1b,
    const unsigned short* __restrict__ w3b, const int* __restrict__ row_token,
    const int* __restrict__ counts, const int* __restrict__ offsets,
    unsigned short* __restrict__ hbuf) {
  int e = blockIdx.z;
  int cnt = counts[e];
  int m0 = blockIdx.y * 128;
  if (m0 >= cnt) return;
  int n0 = blockIdx.x * 128;
  int row_base = offsets[e];

  __shared__ __align__(16) unsigned short lA[2][128 * 32];
  __shared__ __align__(16) unsigned short lB1[2][128 * 32];
  __shared__ __align__(16) unsigned short lB3[2][128 * 32];

  int tid = threadIdx.x;
  int lane = tid & 63, wid = tid >> 6;
  int quad = lane >> 4, l16 = lane & 15;
  int wm = wid >> 1, wn = wid & 1;

  // A staging: 512 16B-chunks (128 rows x 4 segs), 2 per thread; gathered rows
  long aoff[2];
  long boff[2];
#pragma unroll
  for (int it = 0; it < 2; it++) {
    int c = it * 256 + tid;
    int r = c >> 2, seg = c & 3;
    int t = (m0 + r) < cnt ? row_token[row_base + m0 + r] : 0;
    aoff[it] = (long)t * DIM + seg * 8;
    boff[it] = (long)r * DIM + seg * 8;
  }
  const unsigned short* w1p = w1b + (long)e * HIDDEN * DIM + (long)n0 * DIM;
  const unsigned short* w3p = w3b + (long)e * HIDDEN * DIM + (long)n0 * DIM;

  f32x4 acc1[4][4], acc3[4][4];
#pragma unroll
  for (int mi = 0; mi < 4; mi++)
#pragma unroll
    for (int ni = 0; ni < 4; ni++) {
      acc1[mi][ni] = (f32x4){0.f, 0.f, 0.f, 0.f};
      acc3[mi][ni] = (f32x4){0.f, 0.f, 0.f, 0.f};
    }

  // prologue: stage k=0 into buf 0  (6 loads/thread)
#pragma unroll
  for (int it = 0; it < 2; it++) {
    int c = it * 256 + tid;
    gl_lds16(xb + aoff[it], &lA[0][c * 8]);
    gl_lds16(w1p + boff[it], &lB1[0][c * 8]);
    gl_lds16(w3p + boff[it], &lB3[0][c * 8]);
  }

  int pc = 0;
  for (int k0 = 0; k0 < DIM; k0 += 32, pc ^= 1) {
    // all waves done reading buf pc^1 (previous compute) before we overwrite it
    BARRIER();
    if (k0 + 32 < DIM) {
      int nb = pc ^ 1, kn = k0 + 32;
#pragma unroll
      for (int it = 0; it < 2; it++) {
        int c = it * 256 + tid;
        gl_lds16(xb + aoff[it] + kn, &lA[nb][c * 8]);
        gl_lds16(w1p + boff[it] + kn, &lB1[nb][c * 8]);
        gl_lds16(w3p + boff[it] + kn, &lB3[nb][c * 8]);
      }
      WAIT_VM(6);  // drain previous stage only; 6 prefetch loads stay in flight
    } else {
      WAIT_VM(0);
    }
    BARRIER();  // everyone's current-buffer data landed

    bf16x8 af[4], b1f[4], b3f[4];
#pragma unroll
    for (int i = 0; i < 4; i++) {
      af[i]  = *(const bf16x8*)(const void*)&lA[pc][(wm * 64 + i * 16 + l16) * 32 + quad * 8];
      b1f[i] = *(const bf16x8*)(const void*)&lB1[pc][(wn * 64 + i * 16 + l16) * 32 + quad * 8];
      b3f[i] = *(const bf16x8*)(const void*)&lB3[pc][(wn * 64 + i * 16 + l16) * 32 + quad * 8];
    }
#pragma unroll
    for (int mi = 0; mi < 4; mi++)
#pragma unroll
      for (int ni = 0; ni < 4; ni++) {
        acc1[mi][ni] = __builtin_amdgcn_mfma_f32_16x16x32_bf16(af[mi], b1f[ni], acc1[mi][ni], 0, 0, 0);
        acc3[mi][ni] = __builtin_amdgcn_mfma_f32_16x16x32_bf16(af[mi], b3f[ni], acc3[mi][ni], 0, 0, 0);
      }
  }

#pragma unroll
  for (int mi = 0; mi < 4; mi++) {
#pragma unroll
    for (int r = 0; r < 4; r++) {
      int m = wm * 64 + mi * 16 + quad * 4 + r;
      if (m0 + m < cnt) {
        long rowoff = (long)(row_base + m0 + m) * HIDDEN;
#pragma unroll
        for (int ni = 0; ni < 4; ni++) {
          int n = n0 + wn * 64 + ni * 16 + l16;
          float v1 = acc1[mi][ni][r];
          float v3 = acc3[mi][ni][r];
          float sig = 1.f / (1.f + __expf(-v1));
          hbuf[rowoff + n] = f2bf(v1 * sig * v3);
        }
      }
    }
  }
}

// GEMM2: y[t] += w * (h W2^T), 128x128 tile, K-split 2, pipelined dbuf
__global__ __launch_bounds__(256) void ffn2_fast(
    const unsigned short* __restrict__ hbuf, const unsigned short* __restrict__ w2b,
    const int* __restrict__ row_token, const float* __restrict__ row_weight,
    const int* __restrict__ counts, const int* __restrict__ offsets,
    float* __restrict__ y) {
  int e = blockIdx.z;
  int cnt = counts[e];
  int mt = blockIdx.y >> 1, kh = blockIdx.y & 1;
  int m0 = mt * 128;
  if (m0 >= cnt) return;
  int n0 = blockIdx.x * 128;
  int row_base = offsets[e];
  const int KHALF = HIDDEN / 2;
  int kbeg = kh * KHALF;

  __shared__ __align__(16) unsigned short lA[2][128 * 32];
  __shared__ __align__(16) unsigned short lB[2][128 * 32];

  int tid = threadIdx.x;
  int lane = tid & 63, wid = tid >> 6;
  int quad = lane >> 4, l16 = lane & 15;
  int wm = wid >> 1, wn = wid & 1;

  long aoff[2], boff[2];
#pragma unroll
  for (int it = 0; it < 2; it++) {
    int c = it * 256 + tid;
    int r = c >> 2, seg = c & 3;
    int row = (m0 + r) < cnt ? (row_base + m0 + r) : row_base;
    aoff[it] = (long)row * HIDDEN + seg * 8 + kbeg;
    boff[it] = (long)r * HIDDEN + seg * 8 + kbeg;
  }
  const unsigned short* w2p = w2b + (long)e * DIM * HIDDEN + (long)n0 * HIDDEN;

  f32x4 acc[4][4];
#pragma unroll
  for (int mi = 0; mi < 4; mi++)
#pragma unroll
    for (int ni = 0; ni < 4; ni++) acc[mi][ni] = (f32x4){0.f, 0.f, 0.f, 0.f};

  // prologue: stage k=kbeg into buf 0 (4 loads/thread)
#pragma unroll
  for (int it = 0; it < 2; it++) {
    int c = it * 256 + tid;
    gl_lds16(hbuf + aoff[it], &lA[0][c * 8]);
    gl_lds16(w2p + boff[it], &lB[0][c * 8]);
  }

  int pc = 0;
  for (int k0 = 0; k0 < KHALF; k0 += 32, pc ^= 1) {
    BARRIER();
    if (k0 + 32 < KHALF) {
      int nb = pc ^ 1, kn = k0 + 32;
#pragma unroll
      for (int it = 0; it < 2; it++) {
        int c = it * 256 + tid;
        gl_lds16(hbuf + aoff[it] + kn, &lA[nb][c * 8]);
        gl_lds16(w2p + boff[it] + kn, &lB[nb][c * 8]);
      }
      WAIT_VM(4);
    } else {
      WAIT_VM(0);
    }
    BARRIER();

    bf16x8 af[4], bfr[4];
#pragma unroll
    for (int i = 0; i < 4; i++) {
      af[i]  = *(const bf16x8*)(const void*)&lA[pc][(wm * 64 + i * 16 + l16) * 32 + quad * 8];
      bfr[i] = *(const bf16x8*)(const void*)&lB[pc][(wn * 64 + i * 16 + l16) * 32 + quad * 8];
    }
#pragma unroll
    for (int mi = 0; mi < 4; mi++)
#pragma unroll
      for (int ni = 0; ni < 4; ni++)
        acc[mi][ni] = __builtin_amdgcn_mfma_f32_16x16x32_bf16(af[mi], bfr[ni], acc[mi][ni], 0, 0, 0);
  }

#pragma unroll
  for (int mi = 0; mi < 4; mi++) {
#pragma unroll
    for (int r = 0; r < 4; r++) {
      int m = wm * 64 + mi * 16 + quad * 4 + r;
      if (m0 + m < cnt) {
        int t = row_token[row_base + m0 + m];
        float wgt = row_weight[row_base + m0 + m];
        long yoff = (long)t * DIM + n0 + wn * 64;
#pragma unroll
        for (int ni = 0; ni < 4; ni++)
          atomicAdd(&y[yoff + ni * 16 + l16], wgt * acc[mi][ni][r]);
      }
    }
  }
}

// ======================= SLOW PATH (convert-on-the-fly fallback) =============

__global__ __launch_bounds__(256) void ffn1_slow(
    const float* __restrict__ x, const float* __restrict__ w1,
    const float* __restrict__ w3, const int* __restrict__ row_token,
    const int* __restrict__ counts, const int* __restrict__ offsets,
    unsigned short* __restrict__ hbuf) {
  int e = blockIdx.z;
  int cnt = counts[e];
  int m0 = blockIdx.y * 128;
  if (m0 >= cnt) return;
  int n0 = blockIdx.x * 128;
  int row_base = offsets[e];

  __shared__ __align__(16) unsigned short lA[128 * LDSP];
  __shared__ __align__(16) unsigned short lB1[128 * LDSP];
  __shared__ __align__(16) unsigned short lB3[128 * LDSP];

  int tid = threadIdx.x;
  int lane = tid & 63, wid = tid >> 6;
  int quad = lane >> 4, l16 = lane & 15;
  int wm = wid >> 1, wn = wid & 1;

  long aoff[4];
  bool aval[4];
#pragma unroll
  for (int it = 0; it < 4; it++) {
    int linear = it * 256 + tid;
    int r = linear >> 3, c4 = linear & 7;
    bool v = (m0 + r) < cnt;
    aval[it] = v;
    int t = v ? row_token[row_base + m0 + r] : 0;
    aoff[it] = (long)t * DIM + c4 * 4;
  }
  const float* w1p = w1 + (long)e * HIDDEN * DIM;
  const float* w3p = w3 + (long)e * HIDDEN * DIM;

  f32x4 acc1[4][4], acc3[4][4];
#pragma unroll
  for (int mi = 0; mi < 4; mi++)
#pragma unroll
    for (int ni = 0; ni < 4; ni++) {
      acc1[mi][ni] = (f32x4){0.f, 0.f, 0.f, 0.f};
      acc3[mi][ni] = (f32x4){0.f, 0.f, 0.f, 0.f};
    }

  for (int k0 = 0; k0 < DIM; k0 += 32) {
#pragma unroll
    for (int it = 0; it < 4; it++) {
      int linear = it * 256 + tid;
      int r = linear >> 3, c4 = linear & 7;
      float4 v = make_float4(0.f, 0.f, 0.f, 0.f);
      if (aval[it]) v = *(const float4*)(x + aoff[it] + k0);
      ushort4 b;
      b.x = f2bf(v.x); b.y = f2bf(v.y); b.z = f2bf(v.z); b.w = f2bf(v.w);
      *(ushort4*)&lA[r * LDSP + c4 * 4] = b;
    }
#pragma unroll
    for (int it = 0; it < 4; it++) {
      int linear = it * 256 + tid;
      int r = linear >> 3, c4 = linear & 7;
      long boff = (long)(n0 + r) * DIM + k0 + c4 * 4;
      float4 v1 = *(const float4*)(w1p + boff);
      float4 v3 = *(const float4*)(w3p + boff);
      ushort4 b1, b3;
      b1.x = f2bf(v1.x); b1.y = f2bf(v1.y); b1.z = f2bf(v1.z); b1.w = f2bf(v1.w);
      b3.x = f2bf(v3.x); b3.y = f2bf(v3.y); b3.z = f2bf(v3.z); b3.w = f2bf(v3.w);
      *(ushort4*)&lB1[r * LDSP + c4 * 4] = b1;
      *(ushort4*)&lB3[r * LDSP + c4 * 4] = b3;
    }
    __syncthreads();

    bf16x8 af[4], b1f[4], b3f[4];
#pragma unroll
    for (int i = 0; i < 4; i++) {
      af[i]  = *(const bf16x8*)(const void*)&lA[(wm * 64 + i * 16 + l16) * LDSP + quad * 8];
      b1f[i] = *(const bf16x8*)(const void*)&lB1[(wn * 64 + i * 16 + l16) * LDSP + quad * 8];
      b3f[i] = *(const bf16x8*)(const void*)&lB3[(wn * 64 + i * 16 + l16) * LDSP + quad * 8];
    }
#pragma unroll
    for (int mi = 0; mi < 4; mi++)
#pragma unroll
      for (int ni = 0; ni < 4; ni++) {
        acc1[mi][ni] = __builtin_amdgcn_mfma_f32_16x16x32_bf16(af[mi], b1f[ni], acc1[mi][ni], 0, 0, 0);
        acc3[mi][ni] = __builtin_amdgcn_mfma_f32_16x16x32_bf16(af[mi], b3f[ni], acc3[mi][ni], 0, 0, 0);
      }
    __syncthreads();
  }

#pragma unroll
  for (int mi = 0; mi < 4; mi++) {
#pragma unroll
    for (int r = 0; r < 4; r++) {
      int m = wm * 64 + mi * 16 + quad * 4 + r;
      if (m0 + m < cnt) {
        long rowoff = (long)(row_base + m0 + m) * HIDDEN;
#pragma unroll
        for (int ni = 0; ni < 4; ni++) {
          int n = n0 + wn * 64 + ni * 16 + l16;
          float v1 = acc1[mi][ni][r];
          float v3 = acc3[mi][ni][r];
          float sig = 1.f / (1.f + __expf(-v1));
          hbuf[rowoff + n] = f2bf(v1 * sig * v3);
        }
      }
    }
  }
}

__global__ __launch_bounds__(256) void ffn2_slow(
    const unsigned short* __restrict__ hbuf, const float* __restrict__ w2,
    const int* __restrict__ row_token, const float* __restrict__ row_weight,
    const int* __restrict__ counts, const int* __restrict__ offsets,
    float* __restrict__ y) {
  int e = blockIdx.z;
  int cnt = counts[e];
  int m0 = blockIdx.y * 128;
  if (m0 >= cnt) return;
  int n0 = blockIdx.x * 128;
  int row_base = offsets[e];

  __shared__ __align__(16) unsigned short lA[128 * LDSP];
  __shared__ __align__(16) unsigned short lB[128 * LDSP];

  int tid = threadIdx.x;
  int lane = tid & 63, wid = tid >> 6;
  int quad = lane >> 4, l16 = lane & 15;
  int wm = wid >> 1, wn = wid & 1;

  const float* w2p = w2 + (long)e * DIM * HIDDEN;

  f32x4 acc[4][4];
#pragma unroll
  for (int mi = 0; mi < 4; mi++)
#pragma unroll
    for (int ni = 0; ni < 4; ni++) acc[mi][ni] = (f32x4){0.f, 0.f, 0.f, 0.f};

  for (int k0 = 0; k0 < HIDDEN; k0 += 32) {
#pragma unroll
    for (int it = 0; it < 2; it++) {
      int linear = it * 256 + tid;
      int r = linear >> 2, c8 = linear & 3;
      float4 v = make_float4(0.f, 0.f, 0.f, 0.f);
      if (m0 + r < cnt)
        v = *(const float4*)(hbuf + (long)(row_base + m0 + r) * HIDDEN + k0 + c8 * 8);
      *(float4*)&lA[r * LDSP + c8 * 8] = v;
    }
#pragma unroll
    for (int it = 0; it < 4; it++) {
      int linear = it * 256 + tid;
      int r = linear >> 3, c4 = linear & 7;
      float4 v = *(const float4*)(w2p + (long)(n0 + r) * HIDDEN + k0 + c4 * 4);
      ushort4 b;
      b.x = f2bf(v.x); b.y = f2bf(v.y); b.z = f2bf(v.z); b.w = f2bf(v.w);
      *(ushort4*)&lB[r * LDSP + c4 * 4] = b;
    }
    __syncthreads();

    bf16x8 af[4], bfr[4];
#pragma unroll
    for (int i = 0; i < 4; i++) {
      af[i]  = *(const bf16x8*)(const void*)&lA[(wm * 64 + i * 16 + l16) * LDSP + quad * 8];
      bfr[i] = *(const bf16x8*)(const void*)&lB[(wn * 64 + i * 16 + l16) * LDSP + quad * 8];
    }
#pragma unroll
    for (int mi = 0; mi < 4; mi++)
#pragma unroll
      for (int ni = 0; ni < 4; ni++)
        acc[mi][ni] = __builtin_amdgcn_mfma_f32_16x16x32_bf16(af[mi], bfr[ni], acc[mi][ni], 0, 0, 0);
    __syncthreads();
  }

#pragma unroll
  for (int mi = 0; mi < 4; mi++) {
#pragma unroll
    for (int r = 0; r < 4; r++) {
      int m = wm * 64 + mi * 16 + quad * 4 + r;
      if (m0 + m < cnt) {
        int t = row_token[row_base + m0 + m];
        float wgt = row_weight[row_base + m0 + m];
        long yoff = (long)t * DIM + n0 + wn * 64;
#pragma unroll
        for (int ni = 0; ni < 4; ni++)
          atomicAdd(&y[yoff + ni * 16 + l16], wgt * acc[mi][ni][r]);
      }
    }
  }
}

extern "C" void kernel_launch(void* const* d_in, const int* in_sizes, int n_in,
                              void* d_out, int out_size, void* d_ws, size_t ws_size,
                              hipStream_t stream) {
  const float* x = (const float*)d_in[0];
  const float* gw = (const float*)d_in[1];
  const float* w1 = (const float*)d_in[2];
  const float* w2 = (const float*)d_in[3];
  const float* w3 = (const float*)d_in[4];
  float* y = (float*)d_out;

  char* ws = (char*)d_ws;
  int* row_token = (int*)ws;
  float* row_weight = (float*)(ws + 16384);
  int* counts = (int*)(ws + 32768);
  int* offsets = (int*)(ws + 32768 + 32);
  int* tok_idx = (int*)(ws + 32896);
  float* tok_w = (float*)(ws + 32896 + 16384);
  const size_t HBUF_OFF = 65664;                        // 4096*4096 bf16 = 33,554,432
  const size_t XB_OFF   = HBUF_OFF + 33554432ull;       // 2048*1024 bf16 = 4,194,304
  const size_t W1B_OFF  = XB_OFF + 4194304ull;          // 33,554,432 bf16 = 67,108,864
  const size_t W2B_OFF  = W1B_OFF + 67108864ull;
  const size_t W3B_OFF  = W2B_OFF + 67108864ull;
  const size_t NEED     = W3B_OFF + 67108864ull;        // = 239,140,992
  unsigned short* hbuf = (unsigned short*)(ws + HBUF_OFF);

  hipMemsetAsync(d_out, 0, (size_t)T_TOKENS * DIM * sizeof(float), stream);
  gate_kernel<<<T_TOKENS / 4, 256, 0, stream>>>(x, gw, tok_idx, tok_w);
  scatter_kernel<<<1, 256, 0, stream>>>(tok_idx, tok_w, row_token, row_weight, counts, offsets);

  if (ws_size >= NEED) {
    unsigned short* xb  = (unsigned short*)(ws + XB_OFF);
    unsigned short* w1b = (unsigned short*)(ws + W1B_OFF);
    unsigned short* w2b = (unsigned short*)(ws + W2B_OFF);
    unsigned short* w3b = (unsigned short*)(ws + W3B_OFF);
    const int NW8 = NUM_EXPERTS * HIDDEN * DIM / 8;     // 4,194,304
    cast_kernel<<<512, 256, 0, stream>>>(x, xb, T_TOKENS * DIM / 8);
    cast_kernel<<<2048, 256, 0, stream>>>(w1, w1b, NW8);
    cast_kernel<<<2048, 256, 0, stream>>>(w3, w3b, NW8);
    cast_kernel<<<2048, 256, 0, stream>>>(w2, w2b, NW8);
    ffn1_fast<<<dim3(HIDDEN / 128, TOTAL_ROWS / 128, NUM_EXPERTS), 256, 0, stream>>>(
        xb, w1b, w3b, row_token, counts, offsets, hbuf);
    ffn2_fast<<<dim3(DIM / 128, (TOTAL_ROWS / 128) * 2, NUM_EXPERTS), 256, 0, stream>>>(
        hbuf, w2b, row_token, row_weight, counts, offsets, y);
  } else {
    ffn1_slow<<<dim3(HIDDEN / 128, TOTAL_ROWS / 128, NUM_EXPERTS), 256, 0, stream>>>(
        x, w1, w3, row_token, counts, offsets, hbuf);
    ffn2_slow<<<dim3(DIM / 128, TOTAL_ROWS / 128, NUM_EXPERTS), 256, 0, stream>>>(
        hbuf, w2, row_token, row_weight, counts, offsets, y);
  }
}